// Round 1
// baseline (80.336 us; speedup 1.0000x reference)
//
#include <hip/hip_runtime.h>
#include <math.h>

#define B_ 32
#define N_ 1024
#define H_ 768
#define A_ 8
#define TOPK_ 20

__device__ __forceinline__ float wsum(float x) {
#pragma unroll
    for (int off = 32; off > 0; off >>= 1) x += __shfl_xor(x, off);
    return x;
}

// ---------------------------------------------------------------------------
// K1: top-20 indicators for a_idx/b_idx rows, Dv, De.  grid=B, block=1024.
// ---------------------------------------------------------------------------
__global__ __launch_bounds__(1024) void k1_ind(
    const float* __restrict__ att, const int* __restrict__ a_idx,
    const int* __restrict__ b_idx, const float* __restrict__ speak_all,
    float* __restrict__ aind, float* __restrict__ bind,
    float* __restrict__ Dv, float* __restrict__ De)
{
    const int b = blockIdx.x;
    const int tid = threadIdx.x;
    const int w = tid >> 6, lane = tid & 63;
    __shared__ float s_ind[2][N_];
    __shared__ float s_red[3][16];

    s_ind[0][tid] = 0.f;
    s_ind[1][tid] = 0.f;
    __syncthreads();

    // one wave per selected row: waves 0-7 -> a_idx, 8-15 -> b_idx
    const int which = w >> 3;
    const int r = w & 7;
    const int idx = which ? b_idx[b * A_ + r] : a_idx[b * A_ + r];
    if (idx != 0) {  // mask = (idx != 0): rows with idx==0 contribute nothing
        const float* row = att + ((size_t)b * N_ + idx) * N_;
        float v[16];
#pragma unroll
        for (int k = 0; k < 16; ++k) v[k] = row[(k << 6) + lane];
        float* dst = s_ind[which];
        for (int t = 0; t < TOPK_; ++t) {
            float bv = v[0]; int bk = 0;
#pragma unroll
            for (int k = 1; k < 16; ++k)
                if (v[k] > bv) { bv = v[k]; bk = k; }   // strict > keeps lower col on tie
            int bc = (bk << 6) + lane;
#pragma unroll
            for (int off = 32; off > 0; off >>= 1) {
                float ov = __shfl_xor(bv, off);
                int oc = __shfl_xor(bc, off);
                if (ov > bv || (ov == bv && oc < bc)) { bv = ov; bc = oc; }
            }
            if (lane == 0) dst[bc] = 1.f;      // benign same-value races across waves
            if (lane == (bc & 63)) v[bc >> 6] = -INFINITY;
        }
    }
    __syncthreads();

    const float sa = s_ind[0][tid], sb = s_ind[1][tid];
    const float ss = speak_all[(size_t)b * 3 * N_ + tid];
    aind[b * N_ + tid] = sa;
    bind[b * N_ + tid] = sb;
    Dv[b * N_ + tid] = 1.f / sqrtf(sa + sb + ss + 1.f);

    float p[3] = {sa, sb, ss};
#pragma unroll
    for (int e = 0; e < 3; ++e) {
        float x = wsum(p[e]);
        if (lane == 0) s_red[e][w] = x;
    }
    __syncthreads();
    if (tid < 3) {
        float s = 0.f;
        for (int i = 0; i < 16; ++i) s += s_red[tid][i];
        De[b * 3 + tid] = 1.f / sqrtf(s);
    }
}

// ---------------------------------------------------------------------------
// K2: Hyper = Hyper0 @ att.  grid=(32 col-chunks, B), block=256 (cx8 x ry32).
// Each block owns 32 att columns for one batch, loops all rows, skips rows
// with all-zero weights.  No atomics: LDS reduce across ry, plain stores.
// ---------------------------------------------------------------------------
__global__ __launch_bounds__(256) void k2_hyper(
    const float* __restrict__ att, const float* __restrict__ aind,
    const float* __restrict__ bind, const float* __restrict__ speak_all,
    float* __restrict__ Hyper)
{
    const int b = blockIdx.y;
    const int col0 = blockIdx.x * 32;
    const int tid = threadIdx.x;
    const int cx = tid & 7, ry = tid >> 3;
    __shared__ float lds[256 * 13];   // weights (3072) aliased by reduce scratch (3328)
    float* w0 = lds;
    float* w1 = lds + N_;
    float* w2 = lds + 2 * N_;

    for (int n = tid; n < N_; n += 256) {
        w0[n] = aind[b * N_ + n];
        w1[n] = bind[b * N_ + n];
        w2[n] = speak_all[(size_t)b * 3 * N_ + n];
    }
    __syncthreads();

    float a0x=0,a0y=0,a0z=0,a0w=0, a1x=0,a1y=0,a1z=0,a1w=0, a2x=0,a2y=0,a2z=0,a2w=0;
    const float* base = att + (size_t)b * N_ * N_ + col0 + cx * 4;
    for (int n = ry; n < N_; n += 32) {
        const float x0 = w0[n], x1 = w1[n], x2 = w2[n];
        if (x0 == 0.f && x1 == 0.f && x2 == 0.f) continue;  // skip unused att rows
        const float4 v = *(const float4*)(base + (size_t)n * N_);
        a0x += x0*v.x; a0y += x0*v.y; a0z += x0*v.z; a0w += x0*v.w;
        a1x += x1*v.x; a1y += x1*v.y; a1z += x1*v.z; a1w += x1*v.w;
        a2x += x2*v.x; a2y += x2*v.y; a2z += x2*v.z; a2w += x2*v.w;
    }
    __syncthreads();

    float vals[12] = {a0x,a0y,a0z,a0w, a1x,a1y,a1z,a1w, a2x,a2y,a2z,a2w};
    float* scr = lds;   // stride 13 to avoid bank conflicts
#pragma unroll
    for (int k = 0; k < 12; ++k) scr[tid * 13 + k] = vals[k];
    __syncthreads();
    for (int s = 16; s > 0; s >>= 1) {
        if (ry < s) {
#pragma unroll
            for (int k = 0; k < 12; ++k)
                scr[tid * 13 + k] += scr[(tid + s * 8) * 13 + k];
        }
        __syncthreads();
    }
    if (ry == 0) {
#pragma unroll
        for (int e = 0; e < 3; ++e)
#pragma unroll
            for (int j = 0; j < 4; ++j)
                Hyper[(size_t)(b * 3 + e) * N_ + col0 + cx * 4 + j] = scr[tid * 13 + e * 4 + j];
    }
}

// ---------------------------------------------------------------------------
// K4: one pass over h computing U = Hyper_att@h and G[e]=sum Hyper[e,n]Dv[n]h[n].
// grid=(24 col-chunks, B), block=256 (cx8 x ry32).  Softmax stats (m,Z) are
// recomputed per block from LDS-resident Hyper (tiny, removes a kernel).
// ---------------------------------------------------------------------------
__global__ __launch_bounds__(256) void k4_ug(
    const float* __restrict__ h, const float* __restrict__ Hyper,
    const float* __restrict__ Dv, float* __restrict__ U, float* __restrict__ G)
{
    const int b = blockIdx.y;
    const int col0 = blockIdx.x * 32;
    const int tid = threadIdx.x;
    const int cx = tid & 7, ry = tid >> 3;
    const int lane = tid & 63, wv = tid >> 6;
    __shared__ float lds[256 * 25];   // sH(3072)+sDv(1024)+rscr(12); reduce scratch 6400
    float* sH = lds;
    float* sDv = lds + 3 * N_;
    float* rscr = lds + 4 * N_;

    for (int n = tid; n < N_; n += 256) {
        sDv[n] = Dv[b * N_ + n];
#pragma unroll
        for (int e = 0; e < 3; ++e)
            sH[e * N_ + n] = Hyper[(size_t)(b * 3 + e) * N_ + n];
    }
    __syncthreads();

    // row-softmax stats for the 3 hyperedges (uniform in registers afterwards)
    float m0 = -INFINITY, m1 = -INFINITY, m2 = -INFINITY;
    for (int n = tid; n < N_; n += 256) {
        m0 = fmaxf(m0, sH[n]); m1 = fmaxf(m1, sH[N_ + n]); m2 = fmaxf(m2, sH[2 * N_ + n]);
    }
#pragma unroll
    for (int off = 32; off > 0; off >>= 1) {
        m0 = fmaxf(m0, __shfl_xor(m0, off));
        m1 = fmaxf(m1, __shfl_xor(m1, off));
        m2 = fmaxf(m2, __shfl_xor(m2, off));
    }
    if (lane == 0) { rscr[wv * 3 + 0] = m0; rscr[wv * 3 + 1] = m1; rscr[wv * 3 + 2] = m2; }
    __syncthreads();
    m0 = fmaxf(fmaxf(rscr[0], rscr[3]), fmaxf(rscr[6], rscr[9]));
    m1 = fmaxf(fmaxf(rscr[1], rscr[4]), fmaxf(rscr[7], rscr[10]));
    m2 = fmaxf(fmaxf(rscr[2], rscr[5]), fmaxf(rscr[8], rscr[11]));
    __syncthreads();
    float s0 = 0.f, s1 = 0.f, s2 = 0.f;
    for (int n = tid; n < N_; n += 256) {
        s0 += expf(sH[n] - m0); s1 += expf(sH[N_ + n] - m1); s2 += expf(sH[2 * N_ + n] - m2);
    }
    s0 = wsum(s0); s1 = wsum(s1); s2 = wsum(s2);
    if (lane == 0) { rscr[wv * 3 + 0] = s0; rscr[wv * 3 + 1] = s1; rscr[wv * 3 + 2] = s2; }
    __syncthreads();
    const float iZ0 = 1.f / (rscr[0] + rscr[3] + rscr[6] + rscr[9]);
    const float iZ1 = 1.f / (rscr[1] + rscr[4] + rscr[7] + rscr[10]);
    const float iZ2 = 1.f / (rscr[2] + rscr[5] + rscr[8] + rscr[11]);
    __syncthreads();

    float u0x=0,u0y=0,u0z=0,u0w=0, u1x=0,u1y=0,u1z=0,u1w=0, u2x=0,u2y=0,u2z=0,u2w=0;
    float g0x=0,g0y=0,g0z=0,g0w=0, g1x=0,g1y=0,g1z=0,g1w=0, g2x=0,g2y=0,g2z=0,g2w=0;
    const float* base = h + (size_t)b * N_ * H_ + col0 + cx * 4;
    for (int n = ry; n < N_; n += 32) {
        const float H0 = sH[n], H1 = sH[N_ + n], H2 = sH[2 * N_ + n];
        const float dv = sDv[n];
        const float w0 = expf(H0 - m0) * iZ0;
        const float w1 = expf(H1 - m1) * iZ1;
        const float w2 = expf(H2 - m2) * iZ2;
        const float gg0 = H0 * dv, gg1 = H1 * dv, gg2 = H2 * dv;
        const float4 v = *(const float4*)(base + (size_t)n * H_);
        u0x += w0*v.x; u0y += w0*v.y; u0z += w0*v.z; u0w += w0*v.w;
        u1x += w1*v.x; u1y += w1*v.y; u1z += w1*v.z; u1w += w1*v.w;
        u2x += w2*v.x; u2y += w2*v.y; u2z += w2*v.z; u2w += w2*v.w;
        g0x += gg0*v.x; g0y += gg0*v.y; g0z += gg0*v.z; g0w += gg0*v.w;
        g1x += gg1*v.x; g1y += gg1*v.y; g1z += gg1*v.z; g1w += gg1*v.w;
        g2x += gg2*v.x; g2y += gg2*v.y; g2z += gg2*v.z; g2w += gg2*v.w;
    }
    __syncthreads();

    float vals[24] = {u0x,u0y,u0z,u0w, u1x,u1y,u1z,u1w, u2x,u2y,u2z,u2w,
                      g0x,g0y,g0z,g0w, g1x,g1y,g1z,g1w, g2x,g2y,g2z,g2w};
    float* scr = lds;   // stride 25: conflict-free
#pragma unroll
    for (int k = 0; k < 24; ++k) scr[tid * 25 + k] = vals[k];
    __syncthreads();
    for (int s = 16; s > 0; s >>= 1) {
        if (ry < s) {
#pragma unroll
            for (int k = 0; k < 24; ++k)
                scr[tid * 25 + k] += scr[(tid + s * 8) * 25 + k];
        }
        __syncthreads();
    }
    if (ry == 0) {
#pragma unroll
        for (int e = 0; e < 3; ++e)
#pragma unroll
            for (int j = 0; j < 4; ++j) {
                U[(size_t)(b * 3 + e) * H_ + col0 + cx * 4 + j] = scr[tid * 25 + e * 4 + j];
                G[(size_t)(b * 3 + e) * H_ + col0 + cx * 4 + j] = scr[tid * 25 + 12 + e * 4 + j];
            }
    }
}

// ---------------------------------------------------------------------------
// K5: finalize.  grid=B, block=256.
// ---------------------------------------------------------------------------
__global__ __launch_bounds__(256) void k5_fin(
    const float* __restrict__ U, const float* __restrict__ G,
    const float* __restrict__ De, const float* __restrict__ Dv,
    const float* __restrict__ aind, const float* __restrict__ bind,
    const float* __restrict__ speak_all,
    const float* __restrict__ W_w, const float* __restrict__ W_b,
    const float* __restrict__ S_w, const float* __restrict__ S_b,
    float* __restrict__ out)
{
    const int b = blockIdx.x, tid = threadIdx.x;
    const int lane = tid & 63, wv = tid >> 6;
    __shared__ float sKh[3 * H_];
    __shared__ float sscore[N_];
    __shared__ float sred[16];
    __shared__ int sidx[4];

    const float* Ub = U + (size_t)b * 3 * H_;
    const float* Gb = G + (size_t)b * 3 * H_;

    // logit[e] = U[e]·W_w + W_b
    float p0 = 0.f, p1 = 0.f, p2 = 0.f;
    for (int j = tid; j < H_; j += 256) {
        const float ww = W_w[j];
        p0 += Ub[j] * ww; p1 += Ub[H_ + j] * ww; p2 += Ub[2 * H_ + j] * ww;
    }
    p0 = wsum(p0); p1 = wsum(p1); p2 = wsum(p2);
    if (lane == 0) { sred[wv * 3 + 0] = p0; sred[wv * 3 + 1] = p1; sred[wv * 3 + 2] = p2; }
    __syncthreads();
    const float wb = W_b[0];
    const float l0 = sred[0] + sred[3] + sred[6] + sred[9]  + wb;
    const float l1 = sred[1] + sred[4] + sred[7] + sred[10] + wb;
    const float l2 = sred[2] + sred[5] + sred[8] + sred[11] + wb;
    const float mx = fmaxf(l0, fmaxf(l1, l2));
    const float e0 = expf(l0 - mx), e1 = expf(l1 - mx), e2 = expf(l2 - mx);
    const float inv = 1.f / (e0 + e1 + e2);
    const float wd0 = e0 * inv * De[b * 3 + 0];
    const float wd1 = e1 * inv * De[b * 3 + 1];
    const float wd2 = e2 * inv * De[b * 3 + 2];

    // Kh[e] = w[e]*De[e]*G[e]
    for (int j = tid; j < H_; j += 256) {
        sKh[j]          = wd0 * Gb[j];
        sKh[H_ + j]     = wd1 * Gb[H_ + j];
        sKh[2 * H_ + j] = wd2 * Gb[2 * H_ + j];
    }
    __syncthreads();

    // q[e] = Kh[e]·S_w
    float q0 = 0.f, q1 = 0.f, q2 = 0.f;
    for (int j = tid; j < H_; j += 256) {
        const float sw = S_w[j];
        q0 += sKh[j] * sw; q1 += sKh[H_ + j] * sw; q2 += sKh[2 * H_ + j] * sw;
    }
    q0 = wsum(q0); q1 = wsum(q1); q2 = wsum(q2);
    if (lane == 0) { sred[wv * 3 + 0] = q0; sred[wv * 3 + 1] = q1; sred[wv * 3 + 2] = q2; }
    __syncthreads();
    q0 = sred[0] + sred[3] + sred[6] + sred[9];
    q1 = sred[1] + sred[4] + sred[7] + sred[10];
    q2 = sred[2] + sred[5] + sred[8] + sred[11];

    // score[n] = Dv[n]*(a*q0 + b*q1 + s*q2) + S_b
    const float sb0 = S_b[0];
    const float* av = aind + b * N_;
    const float* bv2 = bind + b * N_;
    const float* dv = Dv + b * N_;
    const float* sv = speak_all + (size_t)b * 3 * N_;
    for (int n = tid; n < N_; n += 256)
        sscore[n] = dv[n] * (av[n] * q0 + bv2[n] * q1 + sv[n] * q2) + sb0;
    __syncthreads();

    // top-2 (stable: lower index on ties, like lax.top_k)
    int r0;
    {
        float best = -INFINITY; int bi = N_;
        for (int n = tid; n < N_; n += 256) {
            const float s = sscore[n];
            if (s > best || (s == best && n < bi)) { best = s; bi = n; }
        }
#pragma unroll
        for (int off = 32; off > 0; off >>= 1) {
            const float ov = __shfl_xor(best, off); const int oi = __shfl_xor(bi, off);
            if (ov > best || (ov == best && oi < bi)) { best = ov; bi = oi; }
        }
        if (lane == 0) { sred[wv] = best; sidx[wv] = bi; }
        __syncthreads();
        float v = -INFINITY; int i = N_;
        for (int k = 0; k < 4; ++k)
            if (sred[k] > v || (sred[k] == v && sidx[k] < i)) { v = sred[k]; i = sidx[k]; }
        r0 = i;
    }
    __syncthreads();
    int r1;
    {
        float best = -INFINITY; int bi = N_;
        for (int n = tid; n < N_; n += 256) {
            if (n == r0) continue;
            const float s = sscore[n];
            if (s > best || (s == best && n < bi)) { best = s; bi = n; }
        }
#pragma unroll
        for (int off = 32; off > 0; off >>= 1) {
            const float ov = __shfl_xor(best, off); const int oi = __shfl_xor(bi, off);
            if (ov > best || (ov == best && oi < bi)) { best = ov; bi = oi; }
        }
        if (lane == 0) { sred[wv] = best; sidx[wv] = bi; }
        __syncthreads();
        float v = -INFINITY; int i = N_;
        for (int k = 0; k < 4; ++k)
            if (sred[k] > v || (sred[k] == v && sidx[k] < i)) { v = sred[k]; i = sidx[k]; }
        r1 = i;
    }

    // X[r] = Dv[r]*(a[r]*Kh0 + b[r]*Kh1 + s[r]*Kh2)
    float* ob = out + (size_t)b * 2 * H_;
    {
        const float d = dv[r0], wa = av[r0], wbn = bv2[r0], wsv = sv[r0];
        for (int j = tid; j < H_; j += 256)
            ob[j] = d * (wa * sKh[j] + wbn * sKh[H_ + j] + wsv * sKh[2 * H_ + j]);
    }
    {
        const float d = dv[r1], wa = av[r1], wbn = bv2[r1], wsv = sv[r1];
        for (int j = tid; j < H_; j += 256)
            ob[H_ + j] = d * (wa * sKh[j] + wbn * sKh[H_ + j] + wsv * sKh[2 * H_ + j]);
    }
}

extern "C" void kernel_launch(void* const* d_in, const int* in_sizes, int n_in,
                              void* d_out, int out_size, void* d_ws, size_t ws_size,
                              hipStream_t stream)
{
    const float* h         = (const float*)d_in[0];   // (B,N,H)
    const float* att       = (const float*)d_in[1];   // (B,1,N,N)
    const int*   a_idx     = (const int*)d_in[2];     // (B,8)
    const int*   b_idx     = (const int*)d_in[3];     // (B,8)
    /* d_in[4] speak_num unused by the reference math */
    const float* speak_all = (const float*)d_in[5];   // (B,3,N)
    const float* W_w       = (const float*)d_in[6];   // (1,H)
    const float* W_b       = (const float*)d_in[7];   // (1,)
    const float* S_w       = (const float*)d_in[8];   // (1,H)
    const float* S_b       = (const float*)d_in[9];   // (1,)
    float* out = (float*)d_out;

    // workspace layout (floats); ~1.4 MB total, every region fully written
    // before it is read, so no zero-init needed.
    float* ws    = (float*)d_ws;
    float* aind  = ws;                    // B*N
    float* bind  = aind + B_ * N_;        // B*N
    float* Dv    = bind + B_ * N_;        // B*N
    float* De    = Dv + B_ * N_;          // B*3 (pad to 128)
    float* Hyper = De + 128;              // B*3*N
    float* U     = Hyper + B_ * 3 * N_;   // B*3*H
    float* G     = U + B_ * 3 * H_;       // B*3*H

    k1_ind<<<B_, 1024, 0, stream>>>(att, a_idx, b_idx, speak_all, aind, bind, Dv, De);
    k2_hyper<<<dim3(32, B_), 256, 0, stream>>>(att, aind, bind, speak_all, Hyper);
    k4_ug<<<dim3(24, B_), 256, 0, stream>>>(h, Hyper, Dv, U, G);
    k5_fin<<<B_, 256, 0, stream>>>(U, G, De, Dv, aind, bind, speak_all, W_w, W_b, S_w, S_b, out);
}